// Round 1
// 1084.770 us; speedup vs baseline: 2.2407x; 2.2407x over previous
//
#include <hip/hip_runtime.h>
#include <hip/hip_bf16.h>
#include <math.h>

#define SEQ   2048
#define BATCH 2
#define DM    1024
#define NH    16
#define DH    64
#define TOK   (BATCH*SEQ)   // 4096
#define BHN   (BATCH*NH)    // 32

typedef __hip_bfloat16 bf16;
typedef unsigned short u16;
typedef __bf16  bfv8  __attribute__((ext_vector_type(8)));
typedef u16     u16x8 __attribute__((ext_vector_type(8)));
typedef float   f32x4 __attribute__((ext_vector_type(4)));

__device__ __forceinline__ float b2f(bf16 x) { return __bfloat162float(x); }
__device__ __forceinline__ float u2f(u16 v){ union{unsigned u; float f;} t; t.u = ((unsigned)v)<<16; return t.f; }
__device__ __forceinline__ u16   f2u(float f){ union{float f; unsigned u;} t; t.f = f;
    return (u16)((t.u + 0x7FFFu + ((t.u>>16)&1u))>>16); }
__device__ __forceinline__ bfv8  asbf(u16x8 v){ union{u16x8 u; bfv8 b;} t; t.u = v; return t.b; }
#define MFMA16(a,b,c) __builtin_amdgcn_mfma_f32_16x16x32_bf16((a),(b),(c),0,0,0)

// Dual-dtype load/store: fl==1 -> buffer holds fp32, fl==0 -> bf16.
__device__ __forceinline__ float ldf(const void* p, size_t i, int fl) {
    return fl ? ((const float*)p)[i] : b2f(((const bf16*)p)[i]);
}
__device__ __forceinline__ void stf(void* p, size_t i, int fl, float v) {
    if (fl) ((float*)p)[i] = v;
    else    ((bf16*)p)[i]  = __float2bfloat16(v);
}

// ---------------------------------------------------------------------------
// Detect whether float tensors are stored as fp32 or bf16.
// ---------------------------------------------------------------------------
__global__ void detect_dtype(const void* __restrict__ x, int* __restrict__ flag)
{
    __shared__ int s_bad;
    if (threadIdx.x == 0) s_bad = 0;
    __syncthreads();
    const bf16* p = (const bf16*)x;
    int bad = 0;
    for (int i = threadIdx.x; i < 2048; i += 256) {
        float v = b2f(p[i]);
        if (!(fabsf(v) <= 1e4f)) bad = 1;   // also true for NaN
    }
    if (bad) atomicOr(&s_bad, 1);
    __syncthreads();
    if (threadIdx.x == 0) *flag = s_bad;
}

// ---------------------------------------------------------------------------
// prep_x: X (fp32/bf16, [4096][1024]) -> Xhi/Xlo bf16 chunks (hi/lo split).
// ---------------------------------------------------------------------------
__global__ __launch_bounds__(256)
void prep_x(const void* __restrict__ X, u16x8* __restrict__ Xh,
            u16x8* __restrict__ Xl, const int* __restrict__ flag)
{
    const int fl = *flag;
    const size_t i = (size_t)blockIdx.x*256 + threadIdx.x;   // 8-elem chunk
    float f[8];
    if (fl) {
        const float4* p = (const float4*)X;
        float4 a = p[i*2], b = p[i*2+1];
        f[0]=a.x; f[1]=a.y; f[2]=a.z; f[3]=a.w;
        f[4]=b.x; f[5]=b.y; f[6]=b.z; f[7]=b.w;
    } else {
        u16x8 v = ((const u16x8*)X)[i];
        #pragma unroll
        for (int j=0;j<8;++j) f[j] = u2f(v[j]);
    }
    u16x8 h, l;
    #pragma unroll
    for (int j=0;j<8;++j){ h[j] = f2u(f[j]); l[j] = f2u(f[j]-u2f(h[j])); }
    Xh[i] = h; Xl[i] = l;
}

// ---------------------------------------------------------------------------
// prep_w: W ([K=1024][N=1024], fp32/bf16) -> Wt_hi/Wt_lo bf16 [N][K] (transposed
// + hi/lo split) so GEMM B-fragments are contiguous 16B reads.
// ---------------------------------------------------------------------------
__global__ __launch_bounds__(256)
void prep_w(const void* __restrict__ W, u16* __restrict__ Wth,
            u16* __restrict__ Wtl, const int* __restrict__ flag)
{
    const int fl = *flag;
    __shared__ float T[32][33];
    const int t = threadIdx.x;
    const int n0 = blockIdx.x*32, k0 = blockIdx.y*32;
    {
        const int kr = t>>3, nc = (t&7)*4;
        if (fl) {
            float4 v = *(const float4*)((const float*)W + (size_t)(k0+kr)*DM + n0+nc);
            T[kr][nc]=v.x; T[kr][nc+1]=v.y; T[kr][nc+2]=v.z; T[kr][nc+3]=v.w;
        } else {
            ushort4 v = *(const ushort4*)((const u16*)W + (size_t)(k0+kr)*DM + n0+nc);
            T[kr][nc]=u2f(v.x); T[kr][nc+1]=u2f(v.y); T[kr][nc+2]=u2f(v.z); T[kr][nc+3]=u2f(v.w);
        }
    }
    __syncthreads();
    const int nr = t>>3, kc = (t&7)*4;
    ushort4 hv, lv;
    #pragma unroll
    for (int i=0;i<4;++i){
        float f = T[kc+i][nr];
        u16 h = f2u(f); u16 l = f2u(f - u2f(h));
        (&hv.x)[i] = h; (&lv.x)[i] = l;
    }
    *(ushort4*)(Wth + (size_t)(n0+nr)*DM + k0+kc) = hv;
    *(ushort4*)(Wtl + (size_t)(n0+nr)*DM + k0+kc) = lv;
}

// ---------------------------------------------------------------------------
// MFMA GEMM: C[M=4096][N=1024] = A(hi+lo) @ Wt(hi+lo)^T + bias.
// A: bf16 chunks [M][K], B: bf16 chunks [N][K] (K-major both sides).
// 128x64 tile, BK=32, 4 waves (2m x 2n), each wave 64x32 (4x2 16x16 frags).
// 3-term split (HASAL) gives ~fp32 accuracy. MODE: 0=Q/K out, 1=V^T out, 2=dual out.
// ---------------------------------------------------------------------------
template<int MODE, bool HASAL>
__global__ __launch_bounds__(256)
void gemm_mfma(const u16x8* __restrict__ Ah, const u16x8* __restrict__ Al,
               const u16x8* __restrict__ Bh, const u16x8* __restrict__ Bl,
               const void* __restrict__ bias, void* __restrict__ out,
               const int* __restrict__ flag)
{
    const int fl = *flag;
    __shared__ u16x8 AsH[128*4], AsL[128*4], BsH[64*4], BsL[64*4];
    const int t = threadIdx.x;
    const int n0 = blockIdx.x*64, m0 = blockIdx.y*128;
    const int w = t>>6, lane = t&63, g = lane>>4, c = lane&15;
    const int mw = w>>1, nw = w&1;

    f32x4 acc[4][2];
    #pragma unroll
    for (int mi=0; mi<4; ++mi)
        #pragma unroll
        for (int ni=0; ni<2; ++ni){ f32x4 z = {0.f,0.f,0.f,0.f}; acc[mi][ni] = z; }

    for (int k0 = 0; k0 < DM; k0 += 32) {
        const int kc8 = k0 >> 3;
        {   // stage A (512 chunks) and B (256 chunks)
            int idx = t, row = idx>>2, kk = idx&3;
            AsH[idx] = Ah[(size_t)(m0+row)*128 + kc8 + kk];
            if (HASAL) AsL[idx] = Al[(size_t)(m0+row)*128 + kc8 + kk];
            idx = t+256; row = idx>>2; kk = idx&3;
            AsH[idx] = Ah[(size_t)(m0+row)*128 + kc8 + kk];
            if (HASAL) AsL[idx] = Al[(size_t)(m0+row)*128 + kc8 + kk];
            const int brow = t>>2, bkk = t&3;
            BsH[t] = Bh[(size_t)(n0+brow)*128 + kc8 + bkk];
            BsL[t] = Bl[(size_t)(n0+brow)*128 + kc8 + bkk];
        }
        __syncthreads();
        bfv8 af[4], alf[4], bhf[2], blf[2];
        #pragma unroll
        for (int mi=0; mi<4; ++mi){
            af[mi] = asbf(AsH[(mw*64 + mi*16 + c)*4 + g]);
            if (HASAL) alf[mi] = asbf(AsL[(mw*64 + mi*16 + c)*4 + g]);
        }
        #pragma unroll
        for (int ni=0; ni<2; ++ni){
            bhf[ni] = asbf(BsH[(nw*32 + ni*16 + c)*4 + g]);
            blf[ni] = asbf(BsL[(nw*32 + ni*16 + c)*4 + g]);
        }
        #pragma unroll
        for (int mi=0; mi<4; ++mi)
            #pragma unroll
            for (int ni=0; ni<2; ++ni){
                acc[mi][ni] = MFMA16(af[mi], bhf[ni], acc[mi][ni]);
                acc[mi][ni] = MFMA16(af[mi], blf[ni], acc[mi][ni]);
                if (HASAL) acc[mi][ni] = MFMA16(alf[mi], bhf[ni], acc[mi][ni]);
            }
        __syncthreads();
    }
    // epilogue: D mapping col=lane&15, row=(lane>>4)*4+r
    #pragma unroll
    for (int mi=0; mi<4; ++mi)
        #pragma unroll
        for (int ni=0; ni<2; ++ni){
            const int gcol = n0 + nw*32 + ni*16 + c;
            const float bv = ldf(bias, gcol, fl);
            #pragma unroll
            for (int r=0; r<4; ++r){
                const int grow = m0 + mw*64 + mi*16 + g*4 + r;
                const float v = acc[mi][ni][r] + bv;
                if (MODE == 0) {
                    const int b_ = grow>>11, s = grow&(SEQ-1), h = gcol>>6, d = gcol&63;
                    ((u16*)out)[(((size_t)(b_*NH + h))*SEQ + s)*DH + d] = f2u(v);
                } else if (MODE == 1) {
                    const int b_ = grow>>11, s = grow&(SEQ-1), h = gcol>>6, d = gcol&63;
                    ((u16*)out)[(((size_t)(b_*NH + h))*DH + d)*SEQ + s] = f2u(v);
                } else {
                    stf(out, (size_t)grow*DM + gcol, fl, v);
                }
            }
        }
}

// ---------------------------------------------------------------------------
// Fused QK^T + masked softmax -> writes final attn weights P (dual dtype).
// Block: 32 q-rows x one bh. 4 waves split K (512 keys each).
// Pass1: MFMA QK^T, lane-local online (m,l); merge via shfl + LDS.
// Pass2: recompute QK^T, P = exp(s-m)/l, coalesced write via per-wave LDS buf.
// ---------------------------------------------------------------------------
__global__ __launch_bounds__(256)
void qk_softmax(const u16* __restrict__ Q, const u16* __restrict__ K,
                const int* __restrict__ mask, void* __restrict__ d_out_base,
                const int* __restrict__ flag)
{
    const int fl = *flag;
    const size_t esz = fl ? 4 : 2;
    char* attnw = (char*)d_out_base + (size_t)TOK * DM * esz;

    const int t = threadIdx.x, w = t>>6, lane = t&63, g = lane>>4, c = lane&15;
    const int q0 = blockIdx.x*32;
    const int bh = blockIdx.y, b_ = bh>>4;
    const u16* Qb = Q + (size_t)bh*SEQ*DH;
    const u16* Kb = K + (size_t)bh*SEQ*DH;

    __shared__ __align__(16) float pb[4][32][36];
    __shared__ float smw[4][32], slw[4][32];

    bfv8 qa[2][2];
    #pragma unroll
    for (int mf=0; mf<2; ++mf)
        #pragma unroll
        for (int dh=0; dh<2; ++dh)
            qa[mf][dh] = asbf(*(const u16x8*)(Qb + (size_t)(q0 + mf*16 + c)*DH + dh*32 + g*8));

    const int kbase = w*512;
    float mreg[8], lreg[8];
    #pragma unroll
    for (int i=0;i<8;++i){ mreg[i] = -INFINITY; lreg[i] = 0.f; }

    // ---- pass 1: online (m,l), lane-local ----
    for (int tt=0; tt<32; ++tt){
        const int k0 = kbase + tt*16;
        bfv8 kb0 = asbf(*(const u16x8*)(Kb + (size_t)(k0+c)*DH + g*8));
        bfv8 kb1 = asbf(*(const u16x8*)(Kb + (size_t)(k0+c)*DH + 32 + g*8));
        const int mk = mask[b_*SEQ + k0 + c];
        #pragma unroll
        for (int mf=0; mf<2; ++mf){
            f32x4 dz = {0.f,0.f,0.f,0.f};
            dz = MFMA16(qa[mf][0], kb0, dz);
            dz = MFMA16(qa[mf][1], kb1, dz);
            if (mk) {
                #pragma unroll
                for (int r=0; r<4; ++r){
                    const int i = mf*4 + r;
                    const float s = dz[r]*0.125f;
                    const float mo = mreg[i];
                    const float mn = fmaxf(mo, s);
                    if (mn > mo){ lreg[i] = lreg[i]*__expf(mo-mn) + __expf(s-mn); mreg[i] = mn; }
                    else        { lreg[i] += __expf(s - mo); }
                }
            }
        }
    }
    // merge across the 16 lanes that share each row
    #pragma unroll
    for (int i=0;i<8;++i){
        float m = mreg[i], l = lreg[i];
        #pragma unroll
        for (int d2=1; d2<16; d2<<=1){
            const float mo = __shfl_xor(m, d2);
            const float lo = __shfl_xor(l, d2);
            const float mn = fmaxf(m, mo);
            l = (mn > -INFINITY) ? (l*__expf(m-mn) + lo*__expf(mo-mn)) : 0.f;
            m = mn;
        }
        mreg[i] = m; lreg[i] = l;
    }
    if (c == 0){
        #pragma unroll
        for (int i=0;i<8;++i){
            const int row = (i>>2)*16 + g*4 + (i&3);
            smw[w][row] = mreg[i]; slw[w][row] = lreg[i];
        }
    }
    __syncthreads();
    float mrow[8], prinv[8];
    #pragma unroll
    for (int i=0;i<8;++i){
        const int row = (i>>2)*16 + g*4 + (i&3);
        float mg = fmaxf(fmaxf(smw[0][row], smw[1][row]), fmaxf(smw[2][row], smw[3][row]));
        float lg = 0.f;
        if (mg > -INFINITY){
            #pragma unroll
            for (int w2=0; w2<4; ++w2) lg += slw[w2][row]*__expf(smw[w2][row]-mg);
        }
        mrow[i] = mg; prinv[i] = 1.f/lg;
    }

    // ---- pass 2: P = exp(s-m)/l, write 32x32 groups coalesced ----
    for (int grp=0; grp<16; ++grp){
        const int kg = kbase + grp*32;
        #pragma unroll
        for (int sub=0; sub<2; ++sub){
            const int k0 = kg + sub*16;
            bfv8 kb0 = asbf(*(const u16x8*)(Kb + (size_t)(k0+c)*DH + g*8));
            bfv8 kb1 = asbf(*(const u16x8*)(Kb + (size_t)(k0+c)*DH + 32 + g*8));
            const int mk = mask[b_*SEQ + k0 + c];
            #pragma unroll
            for (int mf=0; mf<2; ++mf){
                f32x4 dz = {0.f,0.f,0.f,0.f};
                dz = MFMA16(qa[mf][0], kb0, dz);
                dz = MFMA16(qa[mf][1], kb1, dz);
                #pragma unroll
                for (int r=0; r<4; ++r){
                    const int i = mf*4 + r;
                    float p = 0.f;
                    if (mk) p = __expf(dz[r]*0.125f - mrow[i]) * prinv[i];
                    pb[w][mf*16 + g*4 + r][sub*16 + c] = p;
                }
            }
        }
        const int row = lane>>1, cb = (lane&1)*16;
        if (fl) {
            float* dst = (float*)attnw + ((size_t)bh*SEQ + q0 + row)*SEQ + kg + cb;
            const float4* src = (const float4*)&pb[w][row][cb];
            ((float4*)dst)[0] = src[0]; ((float4*)dst)[1] = src[1];
            ((float4*)dst)[2] = src[2]; ((float4*)dst)[3] = src[3];
        } else {
            u16x8 v0, v1;
            #pragma unroll
            for (int j=0;j<8;++j){ v0[j] = f2u(pb[w][row][cb+j]); v1[j] = f2u(pb[w][row][cb+8+j]); }
            u16* dst = (u16*)attnw + ((size_t)bh*SEQ + q0 + row)*SEQ + kg + cb;
            *(u16x8*)dst = v0; *(u16x8*)(dst+8) = v1;
        }
    }
}

// ---------------------------------------------------------------------------
// PV: AO[b,s,h*64+d] = P(dual) @ V^T. No LDS; P read hi/lo-split for fp32-level
// accuracy. Block: 64 q-rows x bh; 4 waves x 16 q-rows, full K sweep each.
// ---------------------------------------------------------------------------
__global__ __launch_bounds__(256)
void pv_mfma(const void* __restrict__ d_out_base, const u16* __restrict__ Vt,
             u16* __restrict__ AO, const int* __restrict__ flag)
{
    const int fl = *flag;
    const size_t esz = fl ? 4 : 2;
    const char* attnw = (const char*)d_out_base + (size_t)TOK * DM * esz;
    const int t = threadIdx.x, w = t>>6, lane = t&63, g = lane>>4, c = lane&15;
    const int bh = blockIdx.y, b_ = bh>>4, h = bh&15;
    const int q0 = blockIdx.x*64 + w*16;
    const u16* Vb = Vt + (size_t)bh*DH*SEQ;

    f32x4 acc[4];
    #pragma unroll
    for (int dt=0; dt<4; ++dt){ f32x4 z = {0.f,0.f,0.f,0.f}; acc[dt] = z; }

    const size_t prow = ((size_t)bh*SEQ + q0 + c)*SEQ;
    for (int kc=0; kc<64; ++kc){
        const int kb = kc*32 + g*8;
        float f[8];
        if (fl) {
            const float* P = (const float*)attnw;
            float4 v0 = *(const float4*)(P + prow + kb);
            float4 v1 = *(const float4*)(P + prow + kb + 4);
            f[0]=v0.x; f[1]=v0.y; f[2]=v0.z; f[3]=v0.w;
            f[4]=v1.x; f[5]=v1.y; f[6]=v1.z; f[7]=v1.w;
        } else {
            u16x8 v = *(const u16x8*)((const u16*)attnw + prow + kb);
            #pragma unroll
            for (int j=0;j<8;++j) f[j] = u2f(v[j]);
        }
        u16x8 ph, pl;
        #pragma unroll
        for (int j=0;j<8;++j){ ph[j] = f2u(f[j]); pl[j] = f2u(f[j]-u2f(ph[j])); }
        const bfv8 pa = asbf(ph), pz = asbf(pl);
        #pragma unroll
        for (int dt=0; dt<4; ++dt){
            bfv8 vb = asbf(*(const u16x8*)(Vb + (size_t)(dt*16 + c)*SEQ + kb));
            acc[dt] = MFMA16(pa, vb, acc[dt]);
            acc[dt] = MFMA16(pz, vb, acc[dt]);
        }
    }
    #pragma unroll
    for (int dt=0; dt<4; ++dt)
        #pragma unroll
        for (int r=0; r<4; ++r)
            AO[((size_t)(b_*SEQ + q0 + g*4 + r))*DM + h*DH + dt*16 + c] = f2u(acc[dt][r]);
}

// ---------------------------------------------------------------------------
extern "C" void kernel_launch(void* const* d_in, const int* in_sizes, int n_in,
                              void* d_out, int out_size, void* d_ws, size_t ws_size,
                              hipStream_t stream)
{
    const void* x    = d_in[0];
    const int*  mask = (const int*)d_in[1];
    const void* Wq   = d_in[2];  const void* bq = d_in[3];
    const void* Wk   = d_in[4];  const void* bk = d_in[5];
    const void* Wv   = d_in[6];  const void* bv = d_in[7];
    const void* Wo   = d_in[8];  const void* bo = d_in[9];

    // ws layout (24MB + 256B, same peak as previous version):
    // [flag | pad | Qw 8MB | Kw 8MB | Vt 8MB]; AO aliases Qw (Q dead after
    // qk_softmax); Wo^T hi/lo (4MB) aliases Kw (K dead after qk_softmax).
    int*  flag = (int*)d_ws;
    const size_t qkv_elems = (size_t)BHN * SEQ * DH;     // 4,194,304
    u16* Qw = (u16*)((char*)d_ws + 256);
    u16* Kw = Qw + qkv_elems;
    u16* Vt = Kw + qkv_elems;
    u16* AO = Qw;
    u16* Woth = Kw;
    u16* Wotl = Kw + (size_t)DM*DM;

    // scratch carved from d_out's attn region (overwritten by P afterwards;
    // fixed +16MB offset is inside the attn region for both fp32 and bf16).
    char*  scr  = (char*)d_out + (size_t)TOK*DM*4;
    u16x8* Xh   = (u16x8*)scr;
    u16x8* Xl   = Xh + (size_t)TOK*DM/8;
    u16*   Wqth = (u16*)(scr + (size_t)16*1024*1024);
    u16*   Wqtl = Wqth + (size_t)DM*DM;
    u16*   Wkth = Wqtl + (size_t)DM*DM;
    u16*   Wktl = Wkth + (size_t)DM*DM;
    u16*   Wvth = Wktl + (size_t)DM*DM;
    u16*   Wvtl = Wvth + (size_t)DM*DM;

    dim3 blk(256);

    detect_dtype<<<1, blk, 0, stream>>>(x, flag);

    prep_x<<<dim3(TOK*DM/8/256), blk, 0, stream>>>(x, Xh, Xl, flag);
    prep_w<<<dim3(32,32), blk, 0, stream>>>(Wq, Wqth, Wqtl, flag);
    prep_w<<<dim3(32,32), blk, 0, stream>>>(Wk, Wkth, Wktl, flag);
    prep_w<<<dim3(32,32), blk, 0, stream>>>(Wv, Wvth, Wvtl, flag);

    dim3 gg(DM/64, TOK/128);   // 16 x 32
    gemm_mfma<0,true><<<gg, blk, 0, stream>>>(Xh, Xl, (const u16x8*)Wqth,
        (const u16x8*)Wqtl, bq, (void*)Qw, flag);
    gemm_mfma<0,true><<<gg, blk, 0, stream>>>(Xh, Xl, (const u16x8*)Wkth,
        (const u16x8*)Wktl, bk, (void*)Kw, flag);
    gemm_mfma<1,true><<<gg, blk, 0, stream>>>(Xh, Xl, (const u16x8*)Wvth,
        (const u16x8*)Wvtl, bv, (void*)Vt, flag);

    qk_softmax<<<dim3(SEQ/32, BHN), blk, 0, stream>>>(Qw, Kw, mask, d_out, flag);

    prep_w<<<dim3(32,32), blk, 0, stream>>>(Wo, Woth, Wotl, flag);  // K now dead

    pv_mfma<<<dim3(SEQ/64, BHN), blk, 0, stream>>>(d_out, Vt, AO, flag);

    gemm_mfma<2,false><<<gg, blk, 0, stream>>>((const u16x8*)AO, nullptr,
        (const u16x8*)Woth, (const u16x8*)Wotl, bo, d_out, flag);
}

// Round 2
// 947.703 us; speedup vs baseline: 2.5648x; 1.1446x over previous
//
#include <hip/hip_runtime.h>
#include <hip/hip_bf16.h>
#include <math.h>

#define SEQ   2048
#define BATCH 2
#define DM    1024
#define NH    16
#define DH    64
#define TOK   (BATCH*SEQ)   // 4096
#define BHN   (BATCH*NH)    // 32

typedef __hip_bfloat16 bf16;
typedef unsigned short u16;
typedef __bf16  bfv8  __attribute__((ext_vector_type(8)));
typedef u16     u16x8 __attribute__((ext_vector_type(8)));
typedef float   f32x4 __attribute__((ext_vector_type(4)));

__device__ __forceinline__ float b2f(bf16 x) { return __bfloat162float(x); }
__device__ __forceinline__ float u2f(u16 v){ union{unsigned u; float f;} t; t.u = ((unsigned)v)<<16; return t.f; }
__device__ __forceinline__ u16   f2u(float f){ union{float f; unsigned u;} t; t.f = f;
    return (u16)((t.u + 0x7FFFu + ((t.u>>16)&1u))>>16); }
__device__ __forceinline__ bfv8  asbf(u16x8 v){ union{u16x8 u; bfv8 b;} t; t.u = v; return t.b; }
#define MFMA16(a,b,c) __builtin_amdgcn_mfma_f32_16x16x32_bf16((a),(b),(c),0,0,0)

// Dual-dtype load/store: fl==1 -> buffer holds fp32, fl==0 -> bf16.
__device__ __forceinline__ float ldf(const void* p, size_t i, int fl) {
    return fl ? ((const float*)p)[i] : b2f(((const bf16*)p)[i]);
}
__device__ __forceinline__ void stf(void* p, size_t i, int fl, float v) {
    if (fl) ((float*)p)[i] = v;
    else    ((bf16*)p)[i]  = __float2bfloat16(v);
}

// ---------------------------------------------------------------------------
// Detect whether float tensors are stored as fp32 or bf16.
// ---------------------------------------------------------------------------
__global__ void detect_dtype(const void* __restrict__ x, int* __restrict__ flag)
{
    __shared__ int s_bad;
    if (threadIdx.x == 0) s_bad = 0;
    __syncthreads();
    const bf16* p = (const bf16*)x;
    int bad = 0;
    for (int i = threadIdx.x; i < 2048; i += 256) {
        float v = b2f(p[i]);
        if (!(fabsf(v) <= 1e4f)) bad = 1;   // also true for NaN
    }
    if (bad) atomicOr(&s_bad, 1);
    __syncthreads();
    if (threadIdx.x == 0) *flag = s_bad;
}

// ---------------------------------------------------------------------------
// prep_x: X (fp32/bf16, [4096][1024]) -> Xhi/Xlo bf16 chunks (hi/lo split).
// ---------------------------------------------------------------------------
__global__ __launch_bounds__(256)
void prep_x(const void* __restrict__ X, u16x8* __restrict__ Xh,
            u16x8* __restrict__ Xl, const int* __restrict__ flag)
{
    const int fl = *flag;
    const size_t i = (size_t)blockIdx.x*256 + threadIdx.x;   // 8-elem chunk
    float f[8];
    if (fl) {
        const float4* p = (const float4*)X;
        float4 a = p[i*2], b = p[i*2+1];
        f[0]=a.x; f[1]=a.y; f[2]=a.z; f[3]=a.w;
        f[4]=b.x; f[5]=b.y; f[6]=b.z; f[7]=b.w;
    } else {
        u16x8 v = ((const u16x8*)X)[i];
        #pragma unroll
        for (int j=0;j<8;++j) f[j] = u2f(v[j]);
    }
    u16x8 h, l;
    #pragma unroll
    for (int j=0;j<8;++j){ h[j] = f2u(f[j]); l[j] = f2u(f[j]-u2f(h[j])); }
    Xh[i] = h; Xl[i] = l;
}

// ---------------------------------------------------------------------------
// prep_w: W ([K=1024][N=1024], fp32/bf16) -> Wt_hi/Wt_lo bf16 [N][K] (transposed
// + hi/lo split) so GEMM B-fragments are contiguous 16B reads.
// ---------------------------------------------------------------------------
__global__ __launch_bounds__(256)
void prep_w(const void* __restrict__ W, u16* __restrict__ Wth,
            u16* __restrict__ Wtl, const int* __restrict__ flag)
{
    const int fl = *flag;
    __shared__ float T[32][33];
    const int t = threadIdx.x;
    const int n0 = blockIdx.x*32, k0 = blockIdx.y*32;
    {
        const int kr = t>>3, nc = (t&7)*4;
        if (fl) {
            float4 v = *(const float4*)((const float*)W + (size_t)(k0+kr)*DM + n0+nc);
            T[kr][nc]=v.x; T[kr][nc+1]=v.y; T[kr][nc+2]=v.z; T[kr][nc+3]=v.w;
        } else {
            ushort4 v = *(const ushort4*)((const u16*)W + (size_t)(k0+kr)*DM + n0+nc);
            T[kr][nc]=u2f(v.x); T[kr][nc+1]=u2f(v.y); T[kr][nc+2]=u2f(v.z); T[kr][nc+3]=u2f(v.w);
        }
    }
    __syncthreads();
    const int nr = t>>3, kc = (t&7)*4;
    ushort4 hv, lv;
    #pragma unroll
    for (int i=0;i<4;++i){
        float f = T[kc+i][nr];
        u16 h = f2u(f); u16 l = f2u(f - u2f(h));
        (&hv.x)[i] = h; (&lv.x)[i] = l;
    }
    *(ushort4*)(Wth + (size_t)(n0+nr)*DM + k0+kc) = hv;
    *(ushort4*)(Wtl + (size_t)(n0+nr)*DM + k0+kc) = lv;
}

// ---------------------------------------------------------------------------
// MFMA GEMM: C[M=4096][N=1024] = A(hi+lo) @ Wt(hi+lo)^T + bias.
// 128x64 tile, BK=32, 4 waves (2m x 2n). LDS chunk stride padded 4->5 so
// fragment reads hit all 8 bank-groups ((5c+g)%8 bijective) - was 8-way.
// MODE: 0=Q/K out (B,H,S,Dh), 1=V^T out (B,H,Dh,S), 2=dual out.
// ---------------------------------------------------------------------------
template<int MODE, bool HASAL>
__global__ __launch_bounds__(256)
void gemm_mfma(const u16x8* __restrict__ Ah, const u16x8* __restrict__ Al,
               const u16x8* __restrict__ Bh, const u16x8* __restrict__ Bl,
               const void* __restrict__ bias, void* __restrict__ out,
               const int* __restrict__ flag)
{
    const int fl = *flag;
    __shared__ u16x8 AsH[128*5], AsL[HASAL ? 128*5 : 1], BsH[64*5], BsL[64*5];
    const int t = threadIdx.x;
    const int n0 = blockIdx.x*64, m0 = blockIdx.y*128;
    const int w = t>>6, lane = t&63, g = lane>>4, c = lane&15;
    const int mw = w>>1, nw = w&1;

    f32x4 acc[4][2];
    #pragma unroll
    for (int mi=0; mi<4; ++mi)
        #pragma unroll
        for (int ni=0; ni<2; ++ni){ f32x4 z = {0.f,0.f,0.f,0.f}; acc[mi][ni] = z; }

    for (int k0 = 0; k0 < DM; k0 += 32) {
        const int kc8 = k0 >> 3;
        {   // stage A (512 chunks) and B (256 chunks), padded stride 5
            int row = t>>2, kk = t&3;
            AsH[row*5+kk] = Ah[(size_t)(m0+row)*128 + kc8 + kk];
            if (HASAL) AsL[row*5+kk] = Al[(size_t)(m0+row)*128 + kc8 + kk];
            int row2 = (t+256)>>2;
            AsH[row2*5+kk] = Ah[(size_t)(m0+row2)*128 + kc8 + kk];
            if (HASAL) AsL[row2*5+kk] = Al[(size_t)(m0+row2)*128 + kc8 + kk];
            BsH[row*5+kk] = Bh[(size_t)(n0+row)*128 + kc8 + kk];
            BsL[row*5+kk] = Bl[(size_t)(n0+row)*128 + kc8 + kk];
        }
        __syncthreads();
        bfv8 af[4], alf[4], bhf[2], blf[2];
        #pragma unroll
        for (int mi=0; mi<4; ++mi){
            af[mi] = asbf(AsH[(mw*64 + mi*16 + c)*5 + g]);
            if (HASAL) alf[mi] = asbf(AsL[(mw*64 + mi*16 + c)*5 + g]);
        }
        #pragma unroll
        for (int ni=0; ni<2; ++ni){
            bhf[ni] = asbf(BsH[(nw*32 + ni*16 + c)*5 + g]);
            blf[ni] = asbf(BsL[(nw*32 + ni*16 + c)*5 + g]);
        }
        #pragma unroll
        for (int mi=0; mi<4; ++mi)
            #pragma unroll
            for (int ni=0; ni<2; ++ni){
                acc[mi][ni] = MFMA16(af[mi], bhf[ni], acc[mi][ni]);
                acc[mi][ni] = MFMA16(af[mi], blf[ni], acc[mi][ni]);
                if (HASAL) acc[mi][ni] = MFMA16(alf[mi], bhf[ni], acc[mi][ni]);
            }
        __syncthreads();
    }
    // epilogue: D mapping col=lane&15, row=(lane>>4)*4+r
    #pragma unroll
    for (int mi=0; mi<4; ++mi)
        #pragma unroll
        for (int ni=0; ni<2; ++ni){
            const int gcol = n0 + nw*32 + ni*16 + c;
            const float bv = ldf(bias, gcol, fl);
            #pragma unroll
            for (int r=0; r<4; ++r){
                const int grow = m0 + mw*64 + mi*16 + g*4 + r;
                const float v = acc[mi][ni][r] + bv;
                if (MODE == 0) {
                    const int b_ = grow>>11, s = grow&(SEQ-1), h = gcol>>6, d = gcol&63;
                    ((u16*)out)[(((size_t)(b_*NH + h))*SEQ + s)*DH + d] = f2u(v);
                } else if (MODE == 1) {
                    const int b_ = grow>>11, s = grow&(SEQ-1), h = gcol>>6, d = gcol&63;
                    ((u16*)out)[(((size_t)(b_*NH + h))*DH + d)*SEQ + s] = f2u(v);
                } else {
                    stf(out, (size_t)grow*DM + gcol, fl, v);
                }
            }
        }
}

// ---------------------------------------------------------------------------
// Fused QK^T + masked softmax + PV. Writes final attn weights P (dual dtype)
// AND AO (bf16) in one pass; P is never re-read from HBM.
// Block: 32 q-rows x one bh. 4 waves split K (512 keys each).
// Pass1: MFMA QK^T, lane-local online (m,l); merge via shfl + LDS.
// Pass2: recompute QK^T, P tile -> LDS; write P coalesced; same wave reads
//        P back as hi/lo bf16 A-frags and accumulates O vs V^T fragments.
// End:   4 waves' O partials reduced through LDS, AO written coalesced.
// ---------------------------------------------------------------------------
__global__ __launch_bounds__(256)
void qk_softmax_pv(const u16* __restrict__ Q, const u16* __restrict__ K,
                   const u16* __restrict__ Vt, const int* __restrict__ mask,
                   void* __restrict__ d_out_base, u16* __restrict__ AO,
                   const int* __restrict__ flag)
{
    const int fl = *flag;
    const size_t esz = fl ? 4 : 2;
    char* attnw = (char*)d_out_base + (size_t)TOK * DM * esz;

    const int t = threadIdx.x, w = t>>6, lane = t&63, g = lane>>4, c = lane&15;
    const int q0 = blockIdx.x*32;
    const int bh = blockIdx.y, b_ = bh>>4, h = bh&15;
    const u16* Qb = Q  + (size_t)bh*SEQ*DH;
    const u16* Kb = K  + (size_t)bh*SEQ*DH;
    const u16* Vb = Vt + (size_t)bh*DH*SEQ;

    // sbuf[w]: cols 0..31 = P tile during pass2; cols 0..63 = O partial at end.
    // Stride 68 floats (272B = 17*16B): 16B-aligned rows, conflict-light.
    __shared__ __align__(16) float sbuf[4][32][68];
    __shared__ float smw[4][32], slw[4][32];

    bfv8 qa[2][2];
    #pragma unroll
    for (int mf=0; mf<2; ++mf)
        #pragma unroll
        for (int dh=0; dh<2; ++dh)
            qa[mf][dh] = asbf(*(const u16x8*)(Qb + (size_t)(q0 + mf*16 + c)*DH + dh*32 + g*8));

    const int kbase = w*512;
    float mreg[8], lreg[8];
    #pragma unroll
    for (int i=0;i<8;++i){ mreg[i] = -INFINITY; lreg[i] = 0.f; }

    // ---- pass 1: online (m,l), lane-local ----
    for (int tt=0; tt<32; ++tt){
        const int k0 = kbase + tt*16;
        bfv8 kb0 = asbf(*(const u16x8*)(Kb + (size_t)(k0+c)*DH + g*8));
        bfv8 kb1 = asbf(*(const u16x8*)(Kb + (size_t)(k0+c)*DH + 32 + g*8));
        const int mk = mask[b_*SEQ + k0 + c];
        #pragma unroll
        for (int mf=0; mf<2; ++mf){
            f32x4 dz = {0.f,0.f,0.f,0.f};
            dz = MFMA16(qa[mf][0], kb0, dz);
            dz = MFMA16(qa[mf][1], kb1, dz);
            if (mk) {
                #pragma unroll
                for (int r=0; r<4; ++r){
                    const int i = mf*4 + r;
                    const float s = dz[r]*0.125f;
                    const float mo = mreg[i];
                    const float mn = fmaxf(mo, s);
                    if (mn > mo){ lreg[i] = lreg[i]*__expf(mo-mn) + __expf(s-mn); mreg[i] = mn; }
                    else        { lreg[i] += __expf(s - mo); }
                }
            }
        }
    }
    // merge across the 16 lanes that share each row
    #pragma unroll
    for (int i=0;i<8;++i){
        float m = mreg[i], l = lreg[i];
        #pragma unroll
        for (int d2=1; d2<16; d2<<=1){
            const float mo = __shfl_xor(m, d2);
            const float lo = __shfl_xor(l, d2);
            const float mn = fmaxf(m, mo);
            l = (mn > -INFINITY) ? (l*__expf(m-mn) + lo*__expf(mo-mn)) : 0.f;
            m = mn;
        }
        mreg[i] = m; lreg[i] = l;
    }
    if (c == 0){
        #pragma unroll
        for (int i=0;i<8;++i){
            const int row = (i>>2)*16 + g*4 + (i&3);
            smw[w][row] = mreg[i]; slw[w][row] = lreg[i];
        }
    }
    __syncthreads();
    float mrow[8], prinv[8];
    #pragma unroll
    for (int i=0;i<8;++i){
        const int row = (i>>2)*16 + g*4 + (i&3);
        float mg = fmaxf(fmaxf(smw[0][row], smw[1][row]), fmaxf(smw[2][row], smw[3][row]));
        float lg = 0.f;
        if (mg > -INFINITY){
            #pragma unroll
            for (int w2=0; w2<4; ++w2) lg += slw[w2][row]*__expf(smw[w2][row]-mg);
        }
        mrow[i] = mg; prinv[i] = 1.f/lg;
    }

    // O partial accumulators: D rows q = mf*16+g*4+r, cols d = dt*16+c
    f32x4 oacc[2][4];
    #pragma unroll
    for (int mf=0; mf<2; ++mf)
        #pragma unroll
        for (int dt=0; dt<4; ++dt){ f32x4 z = {0.f,0.f,0.f,0.f}; oacc[mf][dt] = z; }

    // ---- pass 2: P = exp(s-m)/l -> LDS; write P; PV accumulate ----
    for (int grp=0; grp<16; ++grp){
        const int kg = kbase + grp*32;
        #pragma unroll
        for (int sub=0; sub<2; ++sub){
            const int k0 = kg + sub*16;
            bfv8 kb0 = asbf(*(const u16x8*)(Kb + (size_t)(k0+c)*DH + g*8));
            bfv8 kb1 = asbf(*(const u16x8*)(Kb + (size_t)(k0+c)*DH + 32 + g*8));
            const int mk = mask[b_*SEQ + k0 + c];
            #pragma unroll
            for (int mf=0; mf<2; ++mf){
                f32x4 dz = {0.f,0.f,0.f,0.f};
                dz = MFMA16(qa[mf][0], kb0, dz);
                dz = MFMA16(qa[mf][1], kb1, dz);
                #pragma unroll
                for (int r=0; r<4; ++r){
                    const int i = mf*4 + r;
                    float p = 0.f;
                    if (mk) p = __expf(dz[r]*0.125f - mrow[i]) * prinv[i];
                    sbuf[w][mf*16 + g*4 + r][sub*16 + c] = p;
                }
            }
        }
        // coalesced P write (same-wave LDS write->read, DS in-order per wave)
        {
            const int row = lane>>1, cb = (lane&1)*16;
            if (fl) {
                float* dst = (float*)attnw + ((size_t)bh*SEQ + q0 + row)*SEQ + kg + cb;
                const float4* src = (const float4*)&sbuf[w][row][cb];
                ((float4*)dst)[0] = src[0]; ((float4*)dst)[1] = src[1];
                ((float4*)dst)[2] = src[2]; ((float4*)dst)[3] = src[3];
            } else {
                u16x8 v0, v1;
                #pragma unroll
                for (int j=0;j<8;++j){ v0[j] = f2u(sbuf[w][row][cb+j]); v1[j] = f2u(sbuf[w][row][cb+8+j]); }
                u16* dst = (u16*)attnw + ((size_t)bh*SEQ + q0 + row)*SEQ + kg + cb;
                *(u16x8*)dst = v0; *(u16x8*)(dst+8) = v1;
            }
        }
        // PV: A-frag = P rows (hi/lo split), B-frag = V^T rows (bf16)
        #pragma unroll
        for (int mf=0; mf<2; ++mf){
            float pf[8];
            #pragma unroll
            for (int j=0;j<8;++j) pf[j] = sbuf[w][mf*16 + c][g*8 + j];
            u16x8 ph, pl;
            #pragma unroll
            for (int j=0;j<8;++j){ ph[j] = f2u(pf[j]); pl[j] = f2u(pf[j]-u2f(ph[j])); }
            const bfv8 pa = asbf(ph), pz = asbf(pl);
            #pragma unroll
            for (int dt=0; dt<4; ++dt){
                bfv8 vb = asbf(*(const u16x8*)(Vb + (size_t)(dt*16 + c)*SEQ + kg + g*8));
                oacc[mf][dt] = MFMA16(pa, vb, oacc[mf][dt]);
                oacc[mf][dt] = MFMA16(pz, vb, oacc[mf][dt]);
            }
        }
    }

    // ---- cross-wave O reduction + AO write ----
    #pragma unroll
    for (int mf=0; mf<2; ++mf)
        #pragma unroll
        for (int dt=0; dt<4; ++dt)
            #pragma unroll
            for (int r=0; r<4; ++r)
                sbuf[w][mf*16 + g*4 + r][dt*16 + c] = oacc[mf][dt][r];
    __syncthreads();
    {
        const int q = t>>3, dc = (t&7)*8;
        u16x8 pk;
        #pragma unroll
        for (int j=0;j<8;++j){
            float o = sbuf[0][q][dc+j] + sbuf[1][q][dc+j]
                    + sbuf[2][q][dc+j] + sbuf[3][q][dc+j];
            pk[j] = f2u(o);
        }
        *(u16x8*)(AO + ((size_t)(b_*SEQ + q0 + q))*DM + h*DH + dc) = pk;
    }
}

// ---------------------------------------------------------------------------
extern "C" void kernel_launch(void* const* d_in, const int* in_sizes, int n_in,
                              void* d_out, int out_size, void* d_ws, size_t ws_size,
                              hipStream_t stream)
{
    const void* x    = d_in[0];
    const int*  mask = (const int*)d_in[1];
    const void* Wq   = d_in[2];  const void* bq = d_in[3];
    const void* Wk   = d_in[4];  const void* bk = d_in[5];
    const void* Wv   = d_in[6];  const void* bv = d_in[7];
    const void* Wo   = d_in[8];  const void* bo = d_in[9];

    // ws layout (36MB + 256B):
    // [flag | pad | Qw 8MB | Kw 8MB | Vt 8MB | AO 8MB | Woth 2MB | Wotl 2MB]
    // AO gets its own region: the fused kernel reads Q while writing AO, so
    // the old AO<->Qw alias would race across blocks.
    int*  flag = (int*)d_ws;
    const size_t qkv_elems = (size_t)BHN * SEQ * DH;     // 4,194,304
    u16* Qw   = (u16*)((char*)d_ws + 256);
    u16* Kw   = Qw + qkv_elems;
    u16* Vt   = Kw + qkv_elems;
    u16* AO   = Vt + qkv_elems;
    u16* Woth = AO + qkv_elems;
    u16* Wotl = Woth + (size_t)DM*DM;

    // scratch carved from d_out's attn region (overwritten by P afterwards;
    // fixed +16MB offset is inside the attn region for both fp32 and bf16).
    char*  scr  = (char*)d_out + (size_t)TOK*DM*4;
    u16x8* Xh   = (u16x8*)scr;
    u16x8* Xl   = Xh + (size_t)TOK*DM/8;
    u16*   Wqth = (u16*)(scr + (size_t)16*1024*1024);
    u16*   Wqtl = Wqth + (size_t)DM*DM;
    u16*   Wkth = Wqtl + (size_t)DM*DM;
    u16*   Wktl = Wkth + (size_t)DM*DM;
    u16*   Wvth = Wktl + (size_t)DM*DM;
    u16*   Wvtl = Wvth + (size_t)DM*DM;

    dim3 blk(256);

    detect_dtype<<<1, blk, 0, stream>>>(x, flag);

    prep_x<<<dim3(TOK*DM/8/256), blk, 0, stream>>>(x, Xh, Xl, flag);
    prep_w<<<dim3(32,32), blk, 0, stream>>>(Wq, Wqth, Wqtl, flag);
    prep_w<<<dim3(32,32), blk, 0, stream>>>(Wk, Wkth, Wktl, flag);
    prep_w<<<dim3(32,32), blk, 0, stream>>>(Wv, Wvth, Wvtl, flag);
    prep_w<<<dim3(32,32), blk, 0, stream>>>(Wo, Woth, Wotl, flag);  // ws region, no hazard

    dim3 gg(DM/64, TOK/128);   // 16 x 32
    gemm_mfma<0,true><<<gg, blk, 0, stream>>>(Xh, Xl, (const u16x8*)Wqth,
        (const u16x8*)Wqtl, bq, (void*)Qw, flag);
    gemm_mfma<0,true><<<gg, blk, 0, stream>>>(Xh, Xl, (const u16x8*)Wkth,
        (const u16x8*)Wktl, bk, (void*)Kw, flag);
    gemm_mfma<1,true><<<gg, blk, 0, stream>>>(Xh, Xl, (const u16x8*)Wvth,
        (const u16x8*)Wvtl, bv, (void*)Vt, flag);

    qk_softmax_pv<<<dim3(SEQ/32, BHN), blk, 0, stream>>>(Qw, Kw, Vt, mask,
        d_out, AO, flag);

    gemm_mfma<2,false><<<gg, blk, 0, stream>>>((const u16x8*)AO, nullptr,
        (const u16x8*)Woth, (const u16x8*)Wotl, bo, d_out, flag);
}